// Round 7
// baseline (106.924 us; speedup 1.0000x reference)
//
#include <hip/hip_runtime.h>
#include <hip/hip_bf16.h>

#define BATCH 131072
#define PITCH 136   // bf16 elements per tile row (128 + 8 pad, keeps 16B alignment)

typedef __bf16 bf16x8 __attribute__((ext_vector_type(8)));
typedef float floatx4 __attribute__((ext_vector_type(4)));

__device__ __forceinline__ float fast_tanh(float x) {
    // tanh(x) = 1 - 2/(exp(2x)+1); exp overflow -> inf -> rcp -> 0 -> +1 (correct limit)
    float e = __expf(2.0f * x);
    return 1.0f - 2.0f * __builtin_amdgcn_rcpf(e + 1.0f);
}

// d_ws element layout (bf16):
// [0,16384)       W2s : B-frag swizzled W2              (GEMM1: h2pre = h1 @ W2)
// [16384,32768)   GTs : B-frag swizzled G^T, G=W2*C^T   (GEMM2: U = a2 @ G^T)
// [32768,36864)   W1s : B-frag swizzled W1, K pad to 32 (GEMM0: h1pre = [z|t] @ W1)
// [36864,38912)   W3s : B-frag swizzled W3, N pad to 16 (GEMM3: dz = h2 @ W3)
// swizzle: idx = ((kb*N + n)*4 + q)*8 + j  <->  B[k = kb*32 + q*8 + j][n]

__global__ void prep_kernel(const float* __restrict__ W1,
                            const float* __restrict__ W2,
                            const float* __restrict__ W3,
                            __bf16* __restrict__ ws) {
    int idx = blockIdx.x * 256 + threadIdx.x;
    if (idx < 16384) {
        int j = idx & 7, q = (idx >> 3) & 3, n = (idx >> 5) & 127, kb = idx >> 12;
        int k = kb * 32 + q * 8 + j;
        // W2s: B[k=h][n=g] = W2[h][g]
        ws[idx] = (__bf16)W2[k * 128 + n];
        // GTs: B[k=g][n=h] = G[h][g] = W2[h][g] * C[g][h], C[g][h] = sum_d W3[g][d]*W1[d][h]
        float c = 0.0f;
        #pragma unroll
        for (int d = 0; d < 8; ++d) c += W3[k * 8 + d] * W1[d * 128 + n];
        ws[16384 + idx] = (__bf16)(W2[n * 128 + k] * c);
    } else if (idx < 20480) {
        int t = idx - 16384;
        int j = t & 7, q = (t >> 3) & 3, n = t >> 5;   // kb==0 only
        int k = q * 8 + j;
        ws[32768 + t] = (k < 9) ? (__bf16)W1[k * 128 + n] : (__bf16)0.0f;
    } else if (idx < 22528) {
        int t = idx - 20480;
        int j = t & 7, q = (t >> 3) & 3, n = (t >> 5) & 15, kb = t >> 9;
        int k = kb * 32 + q * 8 + j;
        ws[36864 + t] = (n < 8) ? (__bf16)W3[k * 8 + n] : (__bf16)0.0f;
    }
}

// Structure rationale (rounds 0-6 evidence):
//  - W2 staged in LDS; W1 hoisted to 8 reg-frags; GT/W3 streamed from L2.
//  - 256-thr blocks, LDS 51.2 KB -> 3 blocks/CU = 12 waves/CU (needs VGPR
//    <= 170; budget-256 launches have been spill-free: R0 128, R3 72).
//  - launch_bounds(256,2) ONLY. min-waves>=4 attrs trigger the 64-arch-VGPR
//    acc-split + ~200 MB scratch spill (rounds 1-2).
//  - ZERO-TAIL schedule (new): grid = 768 blocks = exactly 3 resident/CU.
//    2048 chunks of 64 samples split 512 blocks x 3 + 256 blocks x 2 --
//    balanced, one scheduling round. R6's 1024-block grid ran 1.33 rounds
//    (256-block tail at 1/3 utilization) and tied R5 despite more waves/CU.
//  - ONE tile round-trip after GEMM1: write h2 only; a2 A-frag derived
//    in-register (aa = 1 - ah2^2, elementwise in k).
__global__ __launch_bounds__(256, 2) void cnf_main(
        const float* __restrict__ z, const float* __restrict__ t_ptr,
        const float* __restrict__ b1g, const float* __restrict__ b2g,
        const float* __restrict__ b3g, const __bf16* __restrict__ ws,
        float* __restrict__ out) {
    __shared__ __bf16 sW2s[16384];          // 32 KB
    __shared__ float sb1[128];
    __shared__ float sb2[128];
    __shared__ __bf16 tile[4][16 * PITCH];  // per-wave private scratch, 4x4352 B

    const int tid = threadIdx.x;
    {
        uint4* dst = (uint4*)sW2s;
        const uint4* src = (const uint4*)ws;
        #pragma unroll
        for (int i = 0; i < 8; ++i) dst[tid + i * 256] = src[tid + i * 256];
        if (tid < 128) { sb1[tid] = b1g[tid]; sb2[tid] = b2g[tid]; }
    }
    __syncthreads();

    const int lane = tid & 63;
    const int w = tid >> 6;
    const int p = lane & 15;       // C/D col, A row (sample), B col
    const int q = lane >> 4;       // quad
    __bf16* T = tile[w];
    const float tval = t_ptr[0];
    const float b3v = (p < 8) ? b3g[p] : 0.0f;
    const bf16x8* W2sv = (const bf16x8*)sW2s;
    const bf16x8* GTv  = (const bf16x8*)(ws + 16384);
    const bf16x8* W1g  = (const bf16x8*)(ws + 32768);
    const bf16x8* W3v  = (const bf16x8*)(ws + 36864);

    // W1 B-frags hoisted to registers (8 x 16 B = 32 VGPR, shared by all its;
    // removes the L2 dependency from the start of each iteration's chain).
    bf16x8 w1f[8];
    #pragma unroll
    for (int nt = 0; nt < 8; ++nt) w1f[nt] = W1g[(nt * 16 + p) * 4 + q];

    // Balanced chunk assignment: 2048 chunks of 64 samples over 768 blocks.
    const int b = blockIdx.x;
    const int nit  = (b < 512) ? 3 : 2;
    const int base = (b < 512) ? b * 3 : 1536 + (b - 512) * 2;

    for (int it = 0; it < nit; ++it) {
        const int s0 = (base + it) * 64 + w * 16;

        // ---- A-frag of X = [z | t | 0 pad to K=32]: A[m=p][k=q*8+j] ----
        bf16x8 ax;
        #pragma unroll
        for (int j = 0; j < 8; ++j) ax[j] = (__bf16)0.0f;
        if (q == 0) {
            const float4 z0 = ((const float4*)(z + (size_t)(s0 + p) * 8))[0];
            const float4 z1 = ((const float4*)(z + (size_t)(s0 + p) * 8))[1];
            ax[0] = (__bf16)z0.x; ax[1] = (__bf16)z0.y;
            ax[2] = (__bf16)z0.z; ax[3] = (__bf16)z0.w;
            ax[4] = (__bf16)z1.x; ax[5] = (__bf16)z1.y;
            ax[6] = (__bf16)z1.z; ax[7] = (__bf16)z1.w;
        } else if (q == 1) {
            ax[0] = (__bf16)tval;   // x[8] = t
        }

        // ---- GEMM0: h1pre = X @ W1 (single K-block), fused tanh/a1, tile h1 ----
        float a1c[32];
        #pragma unroll
        for (int nt = 0; nt < 8; ++nt) {
            const int n = nt * 16 + p;
            floatx4 acc = {0.f, 0.f, 0.f, 0.f};
            acc = __builtin_amdgcn_mfma_f32_16x16x32_bf16(ax, w1f[nt], acc, 0, 0, 0);
            const float bn = sb1[n];
            #pragma unroll
            for (int r = 0; r < 4; ++r) {
                const float h1 = fast_tanh(acc[r] + bn);
                a1c[nt * 4 + r] = __builtin_fmaf(-h1, h1, 1.0f);
                T[(q * 4 + r) * PITCH + n] = (__bf16)h1;   // C/D layout -> tile
            }
        }
        // A-frags of h1 (wave-private LDS, in-order DS ops: no barrier needed)
        bf16x8 ah[4];
        #pragma unroll
        for (int kb = 0; kb < 4; ++kb)
            ah[kb] = *(const bf16x8*)&T[p * PITCH + kb * 32 + q * 8];

        // ---- GEMM1: h2pre = h1 @ W2, fused tanh, h2 -> tile (single round-trip) ----
        #pragma unroll
        for (int nt = 0; nt < 8; ++nt) {
            const int n = nt * 16 + p;
            floatx4 acc = {0.f, 0.f, 0.f, 0.f};
            #pragma unroll
            for (int kb = 0; kb < 4; ++kb)
                acc = __builtin_amdgcn_mfma_f32_16x16x32_bf16(
                        ah[kb], W2sv[(kb * 128 + n) * 4 + q], acc, 0, 0, 0);
            const float bn = sb2[n];
            #pragma unroll
            for (int r = 0; r < 4; ++r) {
                const float h2 = fast_tanh(acc[r] + bn);
                T[(q * 4 + r) * PITCH + n] = (__bf16)h2;
            }
        }
        // h2 A-frags; a2 A-frags derived in-register (a2 = 1 - h2^2, elementwise in k)
        bf16x8 ah2[4];
        bf16x8 aa[4];
        #pragma unroll
        for (int kb = 0; kb < 4; ++kb) {
            ah2[kb] = *(const bf16x8*)&T[p * PITCH + kb * 32 + q * 8];
            #pragma unroll
            for (int j = 0; j < 8; ++j) {
                const float f = (float)ah2[kb][j];
                aa[kb][j] = (__bf16)__builtin_fmaf(-f, f, 1.0f);
            }
        }

        // ---- GEMM3: dz = h2 @ W3 (N padded to 16, only n=p<8 real) ----
        floatx4 acc3 = {0.f, 0.f, 0.f, 0.f};
        #pragma unroll
        for (int kb = 0; kb < 4; ++kb)
            acc3 = __builtin_amdgcn_mfma_f32_16x16x32_bf16(
                    ah2[kb], W3v[(kb * 16 + p) * 4 + q], acc3, 0, 0, 0);
        if (p < 8) {
            #pragma unroll
            for (int r = 0; r < 4; ++r)
                out[(size_t)(s0 + q * 4 + r) * 8 + p] = acc3[r] + b3v;
        }

        // ---- GEMM2: U = a2 @ G^T, fused dot with a1 (trace accumulation) ----
        float tr[4] = {0.f, 0.f, 0.f, 0.f};
        #pragma unroll
        for (int nt = 0; nt < 8; ++nt) {
            const int n = nt * 16 + p;
            floatx4 acc = {0.f, 0.f, 0.f, 0.f};
            #pragma unroll
            for (int kb = 0; kb < 4; ++kb)
                acc = __builtin_amdgcn_mfma_f32_16x16x32_bf16(
                        aa[kb], GTv[(kb * 128 + n) * 4 + q], acc, 0, 0, 0);
            #pragma unroll
            for (int r = 0; r < 4; ++r)
                tr[r] = __builtin_fmaf(a1c[nt * 4 + r], acc[r], tr[r]);
        }

        // ---- reduce trace over the 16 lanes of each quad; write -trace ----
        #pragma unroll
        for (int r = 0; r < 4; ++r) {
            float v = tr[r];
            v += __shfl_xor(v, 1, 64);
            v += __shfl_xor(v, 2, 64);
            v += __shfl_xor(v, 4, 64);
            v += __shfl_xor(v, 8, 64);
            tr[r] = v;
        }
        if (p == 0) {
            #pragma unroll
            for (int r = 0; r < 4; ++r)
                out[(size_t)BATCH * 8 + s0 + q * 4 + r] = -tr[r];
        }
    }
}

extern "C" void kernel_launch(void* const* d_in, const int* in_sizes, int n_in,
                              void* d_out, int out_size, void* d_ws, size_t ws_size,
                              hipStream_t stream) {
    const float* z  = (const float*)d_in[0];
    // d_in[1] = logp_z (unused by the reference math)
    const float* t  = (const float*)d_in[2];
    const float* W1 = (const float*)d_in[3];
    const float* b1 = (const float*)d_in[4];
    const float* W2 = (const float*)d_in[5];
    const float* b2 = (const float*)d_in[6];
    const float* W3 = (const float*)d_in[7];
    const float* b3 = (const float*)d_in[8];
    __bf16* ws = (__bf16*)d_ws;
    float* out = (float*)d_out;

    prep_kernel<<<88, 256, 0, stream>>>(W1, W2, W3, ws);
    cnf_main<<<768, 256, 0, stream>>>(z, t, b1, b2, b3, ws, out);
}

// Round 8
// 96.311 us; speedup vs baseline: 1.1102x; 1.1102x over previous
//
#include <hip/hip_runtime.h>
#include <hip/hip_bf16.h>

#define BATCH 131072
#define PITCH_H 72   // half-tile row: 64 + 8 pad bf16 (144 B = 9x16, keeps 16B align)

typedef __bf16 bf16x8 __attribute__((ext_vector_type(8)));
typedef float floatx4 __attribute__((ext_vector_type(4)));

__device__ __forceinline__ float fast_tanh(float x) {
    // tanh(x) = 1 - 2/(exp(2x)+1); exp overflow -> inf -> rcp -> 0 -> +1 (correct limit)
    float e = __expf(2.0f * x);
    return 1.0f - 2.0f * __builtin_amdgcn_rcpf(e + 1.0f);
}

// d_ws element layout (bf16):
// [0,16384)       W2s : B-frag swizzled W2              (GEMM1: h2pre = h1 @ W2)
// [16384,32768)   GTs : B-frag swizzled G^T, G=W2*C^T   (GEMM2: U = a2 @ G^T)
// [32768,36864)   W1s : B-frag swizzled W1, K pad to 32 (GEMM0: h1pre = [z|t] @ W1)
// [36864,38912)   W3s : B-frag swizzled W3, N pad to 16 (GEMM3: dz = h2 @ W3)
// swizzle: idx = ((kb*N + n)*4 + q)*8 + j  <->  B[k = kb*32 + q*8 + j][n]

__global__ void prep_kernel(const float* __restrict__ W1,
                            const float* __restrict__ W2,
                            const float* __restrict__ W3,
                            __bf16* __restrict__ ws) {
    int idx = blockIdx.x * 256 + threadIdx.x;
    if (idx < 16384) {
        int j = idx & 7, q = (idx >> 3) & 3, n = (idx >> 5) & 127, kb = idx >> 12;
        int k = kb * 32 + q * 8 + j;
        // W2s: B[k=h][n=g] = W2[h][g]
        ws[idx] = (__bf16)W2[k * 128 + n];
        // GTs: B[k=g][n=h] = G[h][g] = W2[h][g] * C[g][h], C[g][h] = sum_d W3[g][d]*W1[d][h]
        float c = 0.0f;
        #pragma unroll
        for (int d = 0; d < 8; ++d) c += W3[k * 8 + d] * W1[d * 128 + n];
        ws[16384 + idx] = (__bf16)(W2[n * 128 + k] * c);
    } else if (idx < 20480) {
        int t = idx - 16384;
        int j = t & 7, q = (t >> 3) & 3, n = t >> 5;   // kb==0 only
        int k = q * 8 + j;
        ws[32768 + t] = (k < 9) ? (__bf16)W1[k * 128 + n] : (__bf16)0.0f;
    } else if (idx < 22528) {
        int t = idx - 20480;
        int j = t & 7, q = (t >> 3) & 3, n = (t >> 5) & 15, kb = t >> 9;
        int k = kb * 32 + q * 8 + j;
        ws[36864 + t] = (n < 8) ? (__bf16)W3[k * 8 + n] : (__bf16)0.0f;
    }
}

// Structure rationale (rounds 0-7 evidence):
//  - R7 counters: 12 waves/CU == 8 waves/CU perf (~40us), VALUBusy 22%,
//    MfmaUtil 7%, no pipe near ceiling -> latency-bound, not occupancy.
//  - Remaining in-loop L2 latency: GEMM2 re-read the WHOLE 32 KB GT from L2
//    every wave-iteration (~32 loads x ~200cy, prefetch-depth capped by
//    VGPRs). R3 proved the identical pattern on W2 cost ~9us. Fix: stage GT
//    in LDS like W2. W3 frags hoisted to regs -> inner loop has NO global
//    loads except z.
//  - To fit 2 blocks/CU (<=80 KB): HALF-WIDTH transpose tile (2.25 KB/wave),
//    two write->read passes per transpose (wave-private, in-order DS, WAR
//    safe). LDS = 32(W2)+32(GT)+9(tiles)+1(bias) = 74 KB -> 8 waves/CU.
//  - launch_bounds(256,2) ONLY: budget-256 is the proven spill-free regime
//    (R0 128, R3 72, R7 128 VGPR). Forcing budget<=128 (min-waves>=4 attrs)
//    triggered the 64-VGPR acc-split + ~200 MB scratch spill (R1/R2).
//  - Grid 1024 x 2it: exactly 2 residency rounds at 2 blocks/CU, uniform
//    per-block work, dynamic balance (R7's static 3/2-split was -17%).
__global__ __launch_bounds__(256, 2) void cnf_main(
        const float* __restrict__ z, const float* __restrict__ t_ptr,
        const float* __restrict__ b1g, const float* __restrict__ b2g,
        const float* __restrict__ b3g, const __bf16* __restrict__ ws,
        float* __restrict__ out) {
    __shared__ __bf16 sW2s[16384];            // 32 KB
    __shared__ __bf16 sGTs[16384];            // 32 KB
    __shared__ float sb1[128];
    __shared__ float sb2[128];
    __shared__ __bf16 tile[4][16 * PITCH_H];  // per-wave half-width scratch, 4x2304 B

    const int tid = threadIdx.x;
    {
        uint4* dst = (uint4*)sW2s;
        const uint4* src = (const uint4*)ws;
        #pragma unroll
        for (int i = 0; i < 8; ++i) dst[tid + i * 256] = src[tid + i * 256];
        uint4* dstg = (uint4*)sGTs;
        const uint4* srcg = (const uint4*)(ws + 16384);
        #pragma unroll
        for (int i = 0; i < 8; ++i) dstg[tid + i * 256] = srcg[tid + i * 256];
        if (tid < 128) { sb1[tid] = b1g[tid]; sb2[tid] = b2g[tid]; }
    }
    __syncthreads();

    const int lane = tid & 63;
    const int w = tid >> 6;
    const int p = lane & 15;       // C/D col, A row (sample), B col
    const int q = lane >> 4;       // quad
    __bf16* T = tile[w];
    const float tval = t_ptr[0];
    const float b3v = (p < 8) ? b3g[p] : 0.0f;
    const bf16x8* W2sv = (const bf16x8*)sW2s;
    const bf16x8* GTsv = (const bf16x8*)sGTs;
    const bf16x8* W1g  = (const bf16x8*)(ws + 32768);
    const bf16x8* W3g  = (const bf16x8*)(ws + 36864);

    // W1 + W3 B-frags hoisted to registers (12 frags = 48 VGPR): no global
    // loads remain in the iteration loop except the z read.
    bf16x8 w1f[8];
    #pragma unroll
    for (int nt = 0; nt < 8; ++nt) w1f[nt] = W1g[(nt * 16 + p) * 4 + q];
    bf16x8 w3f[4];
    #pragma unroll
    for (int kb = 0; kb < 4; ++kb) w3f[kb] = W3g[(kb * 16 + p) * 4 + q];

    #pragma unroll
    for (int it = 0; it < 2; ++it) {
        const int s0 = blockIdx.x * 128 + it * 64 + w * 16;

        // ---- A-frag of X = [z | t | 0 pad to K=32]: A[m=p][k=q*8+j] ----
        bf16x8 ax;
        #pragma unroll
        for (int j = 0; j < 8; ++j) ax[j] = (__bf16)0.0f;
        if (q == 0) {
            const float4 z0 = ((const float4*)(z + (size_t)(s0 + p) * 8))[0];
            const float4 z1 = ((const float4*)(z + (size_t)(s0 + p) * 8))[1];
            ax[0] = (__bf16)z0.x; ax[1] = (__bf16)z0.y;
            ax[2] = (__bf16)z0.z; ax[3] = (__bf16)z0.w;
            ax[4] = (__bf16)z1.x; ax[5] = (__bf16)z1.y;
            ax[6] = (__bf16)z1.z; ax[7] = (__bf16)z1.w;
        } else if (q == 1) {
            ax[0] = (__bf16)tval;   // x[8] = t
        }

        // ---- GEMM0: h1pre = X @ W1, fused tanh/a1; half-tile transpose x2 ----
        float a1c[32];
        bf16x8 ah[4];
        #pragma unroll
        for (int half = 0; half < 2; ++half) {
            #pragma unroll
            for (int nt = half * 4; nt < half * 4 + 4; ++nt) {
                const int n = nt * 16 + p;
                floatx4 acc = {0.f, 0.f, 0.f, 0.f};
                acc = __builtin_amdgcn_mfma_f32_16x16x32_bf16(ax, w1f[nt], acc, 0, 0, 0);
                const float bn = sb1[n];
                #pragma unroll
                for (int r = 0; r < 4; ++r) {
                    const float h1 = fast_tanh(acc[r] + bn);
                    a1c[nt * 4 + r] = __builtin_fmaf(-h1, h1, 1.0f);
                    T[(q * 4 + r) * PITCH_H + (nt - half * 4) * 16 + p] = (__bf16)h1;
                }
            }
            // wave-private LDS, in-order DS ops: no barrier needed (WAR safe)
            ah[half * 2 + 0] = *(const bf16x8*)&T[p * PITCH_H + q * 8];
            ah[half * 2 + 1] = *(const bf16x8*)&T[p * PITCH_H + 32 + q * 8];
        }

        // ---- GEMM1: h2pre = h1 @ W2, fused tanh; half-tile transpose x2 ----
        bf16x8 ah2[4];
        #pragma unroll
        for (int half = 0; half < 2; ++half) {
            #pragma unroll
            for (int nt = half * 4; nt < half * 4 + 4; ++nt) {
                const int n = nt * 16 + p;
                floatx4 acc = {0.f, 0.f, 0.f, 0.f};
                #pragma unroll
                for (int kb = 0; kb < 4; ++kb)
                    acc = __builtin_amdgcn_mfma_f32_16x16x32_bf16(
                            ah[kb], W2sv[(kb * 128 + n) * 4 + q], acc, 0, 0, 0);
                const float bn = sb2[n];
                #pragma unroll
                for (int r = 0; r < 4; ++r) {
                    const float h2 = fast_tanh(acc[r] + bn);
                    T[(q * 4 + r) * PITCH_H + (nt - half * 4) * 16 + p] = (__bf16)h2;
                }
            }
            ah2[half * 2 + 0] = *(const bf16x8*)&T[p * PITCH_H + q * 8];
            ah2[half * 2 + 1] = *(const bf16x8*)&T[p * PITCH_H + 32 + q * 8];
        }

        // a2 A-frags derived in-register (a2 = 1 - h2^2, elementwise in k)
        bf16x8 aa[4];
        #pragma unroll
        for (int kb = 0; kb < 4; ++kb) {
            #pragma unroll
            for (int j = 0; j < 8; ++j) {
                const float f = (float)ah2[kb][j];
                aa[kb][j] = (__bf16)__builtin_fmaf(-f, f, 1.0f);
            }
        }

        // ---- GEMM3: dz = h2 @ W3 (N padded to 16, only n=p<8 real) ----
        floatx4 acc3 = {0.f, 0.f, 0.f, 0.f};
        #pragma unroll
        for (int kb = 0; kb < 4; ++kb)
            acc3 = __builtin_amdgcn_mfma_f32_16x16x32_bf16(
                    ah2[kb], w3f[kb], acc3, 0, 0, 0);
        if (p < 8) {
            #pragma unroll
            for (int r = 0; r < 4; ++r)
                out[(size_t)(s0 + q * 4 + r) * 8 + p] = acc3[r] + b3v;
        }

        // ---- GEMM2: U = a2 @ G^T (G^T staged in LDS), fused dot with a1 ----
        float tr[4] = {0.f, 0.f, 0.f, 0.f};
        #pragma unroll
        for (int nt = 0; nt < 8; ++nt) {
            const int n = nt * 16 + p;
            floatx4 acc = {0.f, 0.f, 0.f, 0.f};
            #pragma unroll
            for (int kb = 0; kb < 4; ++kb)
                acc = __builtin_amdgcn_mfma_f32_16x16x32_bf16(
                        aa[kb], GTsv[(kb * 128 + n) * 4 + q], acc, 0, 0, 0);
            #pragma unroll
            for (int r = 0; r < 4; ++r)
                tr[r] = __builtin_fmaf(a1c[nt * 4 + r], acc[r], tr[r]);
        }

        // ---- reduce trace over the 16 lanes of each quad; write -trace ----
        #pragma unroll
        for (int r = 0; r < 4; ++r) {
            float v = tr[r];
            v += __shfl_xor(v, 1, 64);
            v += __shfl_xor(v, 2, 64);
            v += __shfl_xor(v, 4, 64);
            v += __shfl_xor(v, 8, 64);
            tr[r] = v;
        }
        if (p == 0) {
            #pragma unroll
            for (int r = 0; r < 4; ++r)
                out[(size_t)BATCH * 8 + s0 + q * 4 + r] = -tr[r];
        }
    }
}

extern "C" void kernel_launch(void* const* d_in, const int* in_sizes, int n_in,
                              void* d_out, int out_size, void* d_ws, size_t ws_size,
                              hipStream_t stream) {
    const float* z  = (const float*)d_in[0];
    // d_in[1] = logp_z (unused by the reference math)
    const float* t  = (const float*)d_in[2];
    const float* W1 = (const float*)d_in[3];
    const float* b1 = (const float*)d_in[4];
    const float* W2 = (const float*)d_in[5];
    const float* b2 = (const float*)d_in[6];
    const float* W3 = (const float*)d_in[7];
    const float* b3 = (const float*)d_in[8];
    __bf16* ws = (__bf16*)d_ws;
    float* out = (float*)d_out;

    prep_kernel<<<88, 256, 0, stream>>>(W1, W2, W3, ws);
    cnf_main<<<1024, 256, 0, stream>>>(z, t, b1, b2, b3, ws, out);
}